// Round 2
// baseline (120.198 us; speedup 1.0000x reference)
//
#include <hip/hip_runtime.h>

#define BATCH 500000
#define NF 20
#define NC 8
#define BLOCK 256
#define STRIDE 41   // 40 floats/row + 1 pad: 41 mod 32 odd -> conflict-free scalar reads

__global__ __launch_bounds__(BLOCK) void nb_kernel(const float* __restrict__ x,
                                                   float* __restrict__ out) {
    __shared__ float sx[BLOCK * STRIDE];                    // 41984 B staged input
    __shared__ __align__(16) float sout[BLOCK * NC];        // 8192 B staged output

    const int t = threadIdx.x;
    const long long blockRow0 = (long long)blockIdx.x * BLOCK;

    // ---- coalesced global -> LDS stage: 2560 float4 per block ----
    const float4* xv = (const float4*)x;
    const long long vbase = blockRow0 * 10;          // 40 floats/row = 10 float4/row
    const long long vmax  = (long long)BATCH * 10;
    #pragma unroll
    for (int it = 0; it < 10; ++it) {
        long long vi = vbase + t + it * BLOCK;
        if (vi < vmax) {
            float4 v = xv[vi];
            int fi = (t + it * BLOCK) * 4;           // flat float index within block
            int r = fi / 40, c = fi % 40;            // c is a multiple of 4, no row crossing
            float* dst = &sx[r * STRIDE + c];
            dst[0] = v.x; dst[1] = v.y; dst[2] = v.z; dst[3] = v.w;
        }
    }
    __syncthreads();

    // ---- per-row compute from LDS ----
    long long row = blockRow0 + t;
    if (row < BATCH) {
        const float* rx = &sx[t * STRIDE];
        float feats[NF], mask[NF], term[NF];
        #pragma unroll
        for (int f = 0; f < NF; ++f) feats[f] = rx[f];
        #pragma unroll
        for (int f = 0; f < NF; ++f) mask[f] = rx[NF + f];

        #pragma unroll
        for (int f = 0; f < NF; ++f) {
            float ind = (feats[f] >= 0.0f && feats[f] < 1.0f) ? 1.0f : 0.0f;
            term[f] = (mask[f] > 0.0f) ? ind : 1.0f;
        }

        // prefix/suffix products: class y's non-Gaussian product = pre[y]*suf[y+3]
        float pre[NF + 1], suf[NF + 1];
        pre[0] = 1.0f;
        #pragma unroll
        for (int f = 0; f < NF; ++f) pre[f + 1] = pre[f] * term[f];
        suf[NF] = 1.0f;
        #pragma unroll
        for (int f = NF - 1; f >= 0; --f) suf[f] = suf[f + 1] * term[f];

        const float inv_std = 1.0f / 0.3f;
        const float k_pdf   = 0.3989422804014327f / 0.3f;   // INV_SQRT_2PI / STD

        float probs[NC];
        float total = 0.0f;
        #pragma unroll
        for (int y = 0; y < NC; ++y) {
            float p = pre[y] * suf[y + 3];
            #pragma unroll
            for (int j = 0; j < 3; ++j) {
                int   f = y + j;
                float m = (float)((y >> j) & 1);
                float z = (feats[f] - m) * inv_std;
                float pdf = __expf(-0.5f * z * z) * k_pdf;
                p *= (mask[f] > 0.0f) ? pdf : 1.0f;
            }
            p *= 0.125f;                 // 1/NC before normalizer floor (matches reference)
            probs[y] = p;
            total += p;
        }

        float inv = 1.0f / fmaxf(total, 1e-8f);
        #pragma unroll
        for (int y = 0; y < NC; ++y) sout[t * NC + y] = probs[y] * inv;
    }
    __syncthreads();

    // ---- coalesced LDS -> global write: 512 float4 per block ----
    float4* ov = (float4*)out;
    const long long obase = blockRow0 * 2;           // 8 floats/row = 2 float4/row
    const long long omax  = (long long)BATCH * 2;
    #pragma unroll
    for (int it = 0; it < 2; ++it) {
        long long oi = obase + t + it * BLOCK;
        if (oi < omax) {
            ov[oi] = ((const float4*)sout)[t + it * BLOCK];
        }
    }
}

extern "C" void kernel_launch(void* const* d_in, const int* in_sizes, int n_in,
                              void* d_out, int out_size, void* d_ws, size_t ws_size,
                              hipStream_t stream) {
    const float* x = (const float*)d_in[0];
    float* out = (float*)d_out;
    int blocks = (BATCH + BLOCK - 1) / BLOCK;
    nb_kernel<<<blocks, BLOCK, 0, stream>>>(x, out);
}